// Round 9
// baseline (117.643 us; speedup 1.0000x reference)
//
#include <hip/hip_runtime.h>
#include <hip/hip_cooperative_groups.h>
#include <math.h>

namespace cg = cooperative_groups;

// Problem constants (fixed shapes from setup_inputs)
#define B_    8
#define C_    4
#define H_    256
#define W_    256
#define NCLS  3                      // classes 1..3
#define NBLKC 96                     // cooperative grid: 96 blocks x 256 (co-resident)
#define BIGVAL (1 << 26)             // pad value, never wins the min

// ---------------------------------------------------------------------------
// Single cooperative kernel, three phases separated by grid.sync():
//
// Phase A (vert): block = (class, b, w-tile of 64); 4 waves = 4 h-chunks.
// Per-thread u64 bg bitmask over its 64-row chunk (64 coalesced loads fully
// unrolled for MLP), d_up via clz / d_down via ctz, cross-chunk carries via
// LDS summaries. Ref semantics: no-bg-above => d_up = h+512; g=min(du,dd,512).
// Writes g as u16 to gbuf (3 MB, L2-resident). Computed ONCE (R8's 8x
// redundant recompute was issue-bound: 12.6M loads ~ +20 us -- reverted).
//
// Phase B (horiz): wave handles 16 consecutive rows of one (class,b) plane.
// Wave-private padded LDS row (pads written once; within-wave DS ordering is
// in-order, no barriers). Exactness: D2[x] <= g2[x]; an x' improves only if
// |x-x'| <= g[x]-1 <= rowmax(g)-1 = R, so the radius-R window is exact; all
// candidates are genuine upper bounds; brute-force fallback for R >= 120.
// f32 sqrt (exact for integer D2 < 2^24), fp64 per-lane accumulate,
// per-wave partial -> plain store (deterministic, no atomics).
//
// Phase C: block 0 reduces the 384 partials, normalizes, writes the scalar.
// ---------------------------------------------------------------------------
__global__ __launch_bounds__(256) void fused_coop(const int* __restrict__ mask,
                                                  const float* __restrict__ pred,
                                                  unsigned short* __restrict__ gbuf,
                                                  double* __restrict__ part,
                                                  float* __restrict__ out) {
    cg::grid_group grid = cg::this_grid();
    const int t    = threadIdx.x;
    const int lane = t & 63;
    const int wv   = t >> 6;
    const int blk  = blockIdx.x;                // 0..95

    __shared__ int last_sh[4][64];
    __shared__ int first_sh[4][64];
    __shared__ __align__(16) int ext[4][512];   // per-wave padded g2 row
    __shared__ double bsum[4];

    // ================= Phase A: vertical bitmask scan =================
    {
        const int hc  = wv;                     // h-chunk 0..3
        const int wt  = blk & 3;
        const int b   = (blk >> 2) & 7;
        const int c_i = blk >> 5;               // 0..2
        const int cls = c_i + 1;
        const int w   = (wt << 6) + lane;

        const int* mptr = mask + (b << 16) + (hc << 14) + w;   // row hc*64, col w
        int m[64];
        #pragma unroll
        for (int i = 0; i < 64; ++i) m[i] = mptr[i << 8];      // all independent
        unsigned long long bg = 0ull;
        #pragma unroll
        for (int i = 0; i < 64; ++i)
            bg |= (unsigned long long)(m[i] != cls) << i;

        last_sh[hc][lane]  = bg ? ((hc << 6) + 63 - __builtin_clzll(bg)) : -512;
        first_sh[hc][lane] = bg ? ((hc << 6) + __builtin_ctzll(bg)) : (1 << 20);
        __syncthreads();

        int carry_up = -512;
        #pragma unroll
        for (int k = 0; k < 4; ++k)
            if (k < hc) carry_up = max(carry_up, last_sh[k][lane]);
        int carry_dn = 1 << 20;
        #pragma unroll
        for (int k = 0; k < 4; ++k)
            if (k > hc) carry_dn = min(carry_dn, first_sh[k][lane]);

        unsigned short* gout = gbuf + (((c_i << 3) + b) << 16) + (hc << 14) + w;
        #pragma unroll 4
        for (int i = 0; i < 64; ++i) {
            int h = (hc << 6) + i;
            unsigned long long le = bg & (~0ull >> (63 - i));   // bg rows <= h
            int last = le ? ((hc << 6) + 63 - __builtin_clzll(le)) : carry_up;
            int du = h - last;
            unsigned long long ge = bg >> i;                    // bg rows >= h
            int first = ge ? (h + __builtin_ctzll(ge)) : carry_dn;
            int dd = first - h;
            int g = min(min(du, dd), 512);
            gout[i << 8] = (unsigned short)g;
        }
    }

    grid.sync();   // gbuf visible device-wide

    // ================= Phase B: horizontal window + loss =================
    double sum = 0.0;
    {
        // pads written once; interior [128,384) rewritten per row
        ext[wv][lane]       = BIGVAL;
        ext[wv][64 + lane]  = BIGVAL;
        ext[wv][384 + lane] = BIGVAL;
        ext[wv][448 + lane] = BIGVAL;

        const int gi  = blk * 4 + wv;           // 0..383: 16-row group
        const int c_i = gi >> 7;
        const int b   = (gi >> 4) & 7;
        const int h0  = (gi & 15) << 4;         // rows h0..h0+15
        const int cls = c_i + 1;
        const int x0  = lane << 2;

        const unsigned short* grow = gbuf + (((c_i << 3) + b) << 16) + (h0 << 8) + x0;
        const float*          prow = pred + (((b << 2) + cls) << 16) + (h0 << 8) + x0;

        #pragma unroll 1
        for (int batch = 0; batch < 2; ++batch) {
            ushort4 gv[8];
            float4  pv[8];
            #pragma unroll
            for (int rr = 0; rr < 8; ++rr) {    // prefetch 8 rows (overlapped)
                int ro = ((batch << 3) + rr) << 8;
                gv[rr] = *(const ushort4*)(grow + ro);
                pv[rr] = *(const float4*)(prow + ro);
            }
            #pragma unroll 1
            for (int rr = 0; rr < 8; ++rr) {
                int g0 = gv[rr].x, g1 = gv[rr].y, g2v = gv[rr].z, g3 = gv[rr].w;
                int q0 = g0 * g0, q1 = g1 * g1, q2 = g2v * g2v, q3 = g3 * g3;
                *(int4*)&ext[wv][128 + x0] = make_int4(q0, q1, q2, q3);
                // within-wave DS ops are in-order: prior row's reads precede this write

                int gm = max(max(g0, g1), max(g2v, g3));
                #pragma unroll
                for (int off = 32; off > 0; off >>= 1)
                    gm = max(gm, __shfl_xor(gm, off, 64));
                const int R = gm - 1;

                int D2[4] = { q0, q1, q2, q3 };
                const int* e = &ext[wv][128];

                if (R >= 120) {
                    for (int xp = 0; xp < 256; ++xp) {
                        int s = e[xp];
                        #pragma unroll
                        for (int j = 0; j < 4; ++j) {
                            int d = (x0 + j) - xp;
                            int cand = s + d * d;
                            D2[j] = (cand < D2[j]) ? cand : D2[j];
                        }
                    }
                } else if (R >= 1) {
                    for (int o = 1; o <= R; ++o) {
                        int oo = o * o;
                        #pragma unroll
                        for (int j = 0; j < 4; ++j) {
                            int xj = x0 + j;
                            int c1 = e[xj + o];
                            int c2 = e[xj - o];
                            int cm = (c1 < c2) ? c1 : c2;
                            int cand = cm + oo;
                            D2[j] = (cand < D2[j]) ? cand : D2[j];
                        }
                    }
                }
                // R <= 0: D2 = g2

                sum += (double)(sqrtf((float)D2[0]) * pv[rr].x)
                     + (double)(sqrtf((float)D2[1]) * pv[rr].y)
                     + (double)(sqrtf((float)D2[2]) * pv[rr].z)
                     + (double)(sqrtf((float)D2[3]) * pv[rr].w);
            }
        }
        #pragma unroll
        for (int off = 32; off > 0; off >>= 1) sum += __shfl_xor(sum, off, 64);
        if (lane == 0) part[gi] = sum;          // plain store, deterministic
    }

    grid.sync();   // partials visible device-wide

    // ================= Phase C: final reduction (block 0) =================
    if (blk == 0) {
        double s = part[t] + ((t < 128) ? part[t + 256] : 0.0);   // 384 partials
        #pragma unroll
        for (int off = 32; off > 0; off >>= 1) s += __shfl_xor(s, off, 64);
        if ((t & 63) == 0) bsum[t >> 6] = s;
        __syncthreads();
        if (t == 0) {
            double total = bsum[0] + bsum[1] + bsum[2] + bsum[3];
            double nd = sqrt(131072.0) + 1e-6;      // sqrt(H^2+W^2)+1e-6
            double norm = (double)(float)nd;        // ref casts to float32
            out[0] = (float)(total / norm / ((double)NCLS * (double)(B_ * H_ * W_)));
        }
    }
}

extern "C" void kernel_launch(void* const* d_in, const int* in_sizes, int n_in,
                              void* d_out, int out_size, void* d_ws, size_t ws_size,
                              hipStream_t stream) {
    const float* pred = (const float*)d_in[0];   // [8,4,256,256] f32
    const int*   mask = (const int*)d_in[1];     // [8,256,256] int
    float* out = (float*)d_out;

    char* ws = (char*)d_ws;
    double* part = (double*)ws;                                  // 384 doubles
    unsigned short* gbuf = (unsigned short*)(ws + 65536);        // 3 MB

    void* args[] = { (void*)&mask, (void*)&pred, (void*)&gbuf, (void*)&part, (void*)&out };
    hipLaunchCooperativeKernel((const void*)fused_coop, dim3(NBLKC), dim3(256),
                               args, 0, stream);
}

// Round 10
// 68.949 us; speedup vs baseline: 1.7062x; 1.7062x over previous
//
#include <hip/hip_runtime.h>
#include <math.h>

// Problem constants (fixed shapes from setup_inputs)
#define B_    8
#define C_    4
#define H_    256
#define W_    256
#define NCLS  3                      // classes 1..3
#define NROWS (NCLS * B_ * H_)       // 6144 rows for horizontal pass
#define BIGVAL (1 << 26)             // pad value, never wins the min

// R10 = R7 verbatim (best measured: 68.3 us). Variance probe — structural
// alternatives all measured worse: atomics+fence +30us (R5), redundant
// recompute +8us (R8), cooperative grid.sync +49us (R9).

// ---------------------------------------------------------------------------
// Kernel 1: vertical 1D distance g = min(d_up, d_down, 512) via bitmask scan.
// Block = (class, b, w-tile of 64). 4 waves = 4 h-chunks of 64 rows.
// Thread (hc, lane): fully-unrolled 64 coalesced row loads into registers
// (max memory-level parallelism), builds u64 bg bitmask, then per row derives
// d_up via clz on prefix bits and d_down via ctz on suffix bits; cross-chunk
// carries via 4-entry LDS summaries. Matches ref semantics: no-bg-above =>
// d_up = h+512 (clamped 512); g = min(du, dd, BIG=512).
// ---------------------------------------------------------------------------
__global__ __launch_bounds__(256) void vert_g_kernel(const int* __restrict__ mask,
                                                     unsigned short* __restrict__ gbuf) {
    const int lane = threadIdx.x & 63;
    const int hc   = threadIdx.x >> 6;          // h-chunk 0..3
    const int blk  = blockIdx.x;                // 0..95
    const int wt   = blk & 3;
    const int b    = (blk >> 2) & 7;
    const int c_i  = blk >> 5;                  // 0..2
    const int cls  = c_i + 1;
    const int w    = (wt << 6) + lane;

    __shared__ int last_sh[4][64];              // highest bg row per chunk (or -512)
    __shared__ int first_sh[4][64];             // lowest bg row per chunk (or big)

    const int* mptr = mask + (b << 16) + (hc << 14) + w;   // row hc*64, col w
    int m[64];
    #pragma unroll
    for (int i = 0; i < 64; ++i) m[i] = mptr[i << 8];      // all independent
    unsigned long long bg = 0ull;
    #pragma unroll
    for (int i = 0; i < 64; ++i)
        bg |= (unsigned long long)(m[i] != cls) << i;

    last_sh[hc][lane]  = bg ? ((hc << 6) + 63 - __builtin_clzll(bg)) : -512;
    first_sh[hc][lane] = bg ? ((hc << 6) + __builtin_ctzll(bg)) : (1 << 20);
    __syncthreads();

    int carry_up = -512;                        // last bg row in chunks above
    #pragma unroll
    for (int k = 0; k < 4; ++k)
        if (k < hc) carry_up = max(carry_up, last_sh[k][lane]);
    int carry_dn = 1 << 20;                     // first bg row in chunks below
    #pragma unroll
    for (int k = 0; k < 4; ++k)
        if (k > hc) carry_dn = min(carry_dn, first_sh[k][lane]);

    unsigned short* gout = gbuf + (((c_i << 3) + b) << 16) + (hc << 14) + w;
    #pragma unroll 4
    for (int i = 0; i < 64; ++i) {
        int h = (hc << 6) + i;
        unsigned long long le = bg & (~0ull >> (63 - i));   // bg bits at rows <= h
        int last = le ? ((hc << 6) + 63 - __builtin_clzll(le)) : carry_up;
        int du = h - last;
        unsigned long long ge = bg >> i;                    // bg bits at rows >= h
        int first = ge ? (h + __builtin_ctzll(ge)) : carry_dn;
        int dd = first - h;
        int g = min(min(du, dd), 512);
        gout[i << 8] = (unsigned short)g;
    }
}

// ---------------------------------------------------------------------------
// Kernel 2: exact horizontal lower-envelope + fused loss partial.
// 1536 blocks x 4 waves, ONE row per wave. NO __syncthreads: each wave uses
// only its own ext[wv] slice; wave-internal LDS ordering (lgkmcnt) suffices.
// Both global loads (pred, gbuf) issued up front to overlap latencies.
// Exactness: D2[x] <= g2[x]; an x' improves only if |x-x'| <= g[x]-1 <=
// rowmax(g)-1 = R, so the radius-R windowed search is exact; every candidate
// is a genuine upper bound. Brute-force fallback for large R.
// Each wave stores its own fp64 partial (deterministic, no atomics/fences).
// ---------------------------------------------------------------------------
__global__ __launch_bounds__(256) void horiz_kernel(const unsigned short* __restrict__ gbuf,
                                                    const float* __restrict__ pred,
                                                    double* __restrict__ acc) {
    const int lane = threadIdx.x & 63;
    const int wv   = threadIdx.x >> 6;
    const int row  = blockIdx.x * 4 + wv;       // 0..6143
    const int c_i  = row >> 11;
    const int b    = (row >> 8) & 7;
    const int h    = row & 255;
    const int cls  = c_i + 1;

    __shared__ __align__(16) int ext[4][512];   // per-wave padded g2 row: x = i-128

    const int x0 = lane << 2;
    // issue both independent global loads immediately (overlapped latencies)
    const float* prow = pred + ((((b << 2) + cls) << 8) + h) * 256;
    float4 pv = *(const float4*)(prow + x0);
    ushort4 gv = *(const ushort4*)(gbuf + row * 256 + x0);

    int g0 = gv.x, g1 = gv.y, g2v = gv.z, g3 = gv.w;
    int q0 = g0 * g0, q1 = g1 * g1, q2 = g2v * g2v, q3 = g3 * g3;
    *(int4*)&ext[wv][128 + x0] = make_int4(q0, q1, q2, q3);
    // pads: [0,128) and [384,512)
    ext[wv][lane]       = BIGVAL;
    ext[wv][64 + lane]  = BIGVAL;
    ext[wv][384 + lane] = BIGVAL;
    ext[wv][448 + lane] = BIGVAL;
    // no barrier: single-wave ownership of ext[wv]; lgkmcnt orders ds ops

    // wave max of g -> window radius
    int gm = max(max(g0, g1), max(g2v, g3));
    #pragma unroll
    for (int off = 32; off > 0; off >>= 1) gm = max(gm, __shfl_xor(gm, off, 64));
    const int R = gm - 1;

    int D2[4] = { q0, q1, q2, q3 };
    const int* e = &ext[wv][128];

    if (R >= 120) {
        // brute force over all source columns (rare)
        for (int xp = 0; xp < 256; ++xp) {
            int s = e[xp];
            #pragma unroll
            for (int j = 0; j < 4; ++j) {
                int d = (x0 + j) - xp;
                int cand = s + d * d;
                D2[j] = (cand < D2[j]) ? cand : D2[j];
            }
        }
    } else if (R >= 1) {
        for (int o = 1; o <= R; ++o) {
            int oo = o * o;
            #pragma unroll
            for (int j = 0; j < 4; ++j) {
                int xj = x0 + j;
                int c1 = e[xj + o];
                int c2 = e[xj - o];
                int cm = (c1 < c2) ? c1 : c2;
                int cand = cm + oo;
                D2[j] = (cand < D2[j]) ? cand : D2[j];
            }
        }
    }
    // (R <= 0: all background in window -> D2 = g2)

    // loss terms: f32 sqrt (D2 < 2^24, exact in f32), fp64 accumulate
    double sum = (double)(sqrtf((float)D2[0]) * pv.x)
               + (double)(sqrtf((float)D2[1]) * pv.y)
               + (double)(sqrtf((float)D2[2]) * pv.z)
               + (double)(sqrtf((float)D2[3]) * pv.w);
    #pragma unroll
    for (int off = 32; off > 0; off >>= 1) sum += __shfl_xor(sum, off, 64);
    if (lane == 0) acc[row] = sum;              // plain store, deterministic
}

// ---------------------------------------------------------------------------
// Kernel 3: deterministic final reduction + normalization. 256 threads,
// 24 independent fp64 loads per thread, LDS + shuffle reduce.
// ---------------------------------------------------------------------------
__global__ __launch_bounds__(256) void final_kernel(const double* __restrict__ acc,
                                                    float* __restrict__ out) {
    const int t = threadIdx.x;
    __shared__ double wsum[4];
    double s = 0.0;
    #pragma unroll
    for (int i = 0; i < NROWS / 256; ++i) s += acc[t + i * 256];
    #pragma unroll
    for (int off = 32; off > 0; off >>= 1) s += __shfl_xor(s, off, 64);
    if ((t & 63) == 0) wsum[t >> 6] = s;
    __syncthreads();
    if (t == 0) {
        double total = wsum[0] + wsum[1] + wsum[2] + wsum[3];
        double nd = sqrt(131072.0) + 1e-6;          // sqrt(H^2+W^2)+1e-6
        double norm = (double)(float)nd;            // ref casts to float32
        out[0] = (float)(total / norm / ((double)NCLS * (double)(B_ * H_ * W_)));
    }
}

extern "C" void kernel_launch(void* const* d_in, const int* in_sizes, int n_in,
                              void* d_out, int out_size, void* d_ws, size_t ws_size,
                              hipStream_t stream) {
    const float* pred = (const float*)d_in[0];   // [8,4,256,256] f32
    const int*   mask = (const int*)d_in[1];     // [8,256,256] int
    float* out = (float*)d_out;

    char* ws = (char*)d_ws;
    double* acc = (double*)ws;                                   // 6144 doubles
    unsigned short* gbuf = (unsigned short*)(ws + 65536);        // 3 MB

    vert_g_kernel<<<NCLS * 8 * 4, 256, 0, stream>>>(mask, gbuf);
    horiz_kernel<<<NROWS / 4, 256, 0, stream>>>(gbuf, pred, acc);
    final_kernel<<<1, 256, 0, stream>>>(acc, out);
}